// Round 7
// baseline (1130.917 us; speedup 1.0000x reference)
//
#include <hip/hip_runtime.h>
#include <math.h>

#define HW2 4096

typedef __attribute__((ext_vector_type(8))) short s16x8;
typedef __attribute__((ext_vector_type(4))) short s16x4;
typedef __attribute__((ext_vector_type(4))) float f32x4;
typedef __attribute__((ext_vector_type(4))) int i32x4;

__device__ __forceinline__ unsigned short f2bf(float x) {
  unsigned int u = __float_as_uint(x);
  u += 0x7fff + ((u >> 16) & 1);          // RNE
  return (unsigned short)(u >> 16);
}

__device__ __forceinline__ void async16(void* lds, const void* g) {
  __builtin_amdgcn_global_load_lds(
      (const __attribute__((address_space(1))) void*)g,
      (__attribute__((address_space(3))) void*)lds, 16, 0, 0);
}

// raw buffer load: hardware bounds check (OOB -> returns 0, no fault)
__device__ f32x4 llvm_amdgcn_raw_buffer_load_v4f32(
    i32x4 srsrc, int voffset, int soffset, int aux)
    __asm("llvm.amdgcn.raw.buffer.load.v4f32");

__device__ __forceinline__ i32x4 make_srd(const void* p, unsigned bytes) {
  i32x4 r;
  unsigned long long a = (unsigned long long)p;
  r[0] = (int)(unsigned)a;
  r[1] = (int)(unsigned)(a >> 32);   // base[47:32], stride=0
  r[2] = (int)bytes;                 // num_records (bytes, stride==0)
  r[3] = 0x00020000;                 // raw dword access
  return r;
}

// ---------------------------------------------------------------------------
// fp32 NCHW -> bf16 transposed [b][h][cc][w*32+ci].  Block = (cc, h8, b).
// ---------------------------------------------------------------------------
__global__ __launch_bounds__(256) void tpose_k(
    const float* __restrict__ in, unsigned short* __restrict__ outT, int CC)
{
  __shared__ short sT[32 * 534];
  const int cc = blockIdx.x;
  const int h0 = blockIdx.y * 8;
  const int b  = blockIdx.z;
  const int tid = threadIdx.x;
  const float* ip = in + (size_t)(b * CC + cc) * 32 * 4096;

  for (int e = tid; e < 4096; e += 256) {
    int ci = e >> 7, rem = e & 127;
    int h = rem >> 4, w4 = rem & 15;
    float4 v = *(const float4*)&ip[(size_t)ci * 4096 + (h0 + h) * 64 + w4 * 4];
    short* d = &sT[ci * 534 + h * 66 + w4 * 4];
    d[0] = (short)f2bf(v.x); d[1] = (short)f2bf(v.y);
    d[2] = (short)f2bf(v.z); d[3] = (short)f2bf(v.w);
  }
  __syncthreads();
  unsigned short* ob = outT + (size_t)b * 64 * CC * 2048;
  for (int e = tid; e < 2048; e += 256) {
    int h = e >> 8, rem = e & 255;
    int w = rem >> 2, q = rem & 3;
    s16x8 v;
    #pragma unroll
    for (int j = 0; j < 8; ++j) v[j] = sT[(q * 8 + j) * 534 + h * 66 + w];
    *(s16x8*)&ob[((size_t)(h0 + h) * CC + cc) * 2048 + w * 32 + q * 8] = v;
  }
}

// ---------------------------------------------------------------------------
// Weight prep (coalesced): fp32 OIHW -> bf16 MFMA A-frag order.
// ---------------------------------------------------------------------------
__global__ __launch_bounds__(256) void wprep_k(const float* __restrict__ w,
                                               unsigned short* __restrict__ Wb,
                                               int Cin) {
  __shared__ float sC[32 * 289];
  const int CC = Cin >> 5;
  const int cc = blockIdx.x % CC, cob = blockIdx.x / CC;
  const int tid = threadIdx.x;
  for (int e = tid; e < 2304; e += 256) {
    int co = e / 72, off = e % 72;
    float4 v = *(const float4*)&w[((size_t)(cob * 32 + co) * Cin + cc * 32) * 9 +
                                  off * 4];
    float* d = &sC[co * 289 + off * 4];
    d[0] = v.x; d[1] = v.y; d[2] = v.z; d[3] = v.w;
  }
  __syncthreads();
  unsigned short* ob = Wb + (size_t)(cob * CC + cc) * 9216;
  for (int e = tid; e < 1152; e += 256) {
    int ln = e & 15, q = (e >> 4) & 3, mt = (e >> 6) & 1, t = e >> 7;
    s16x8 v;
    #pragma unroll
    for (int j = 0; j < 8; ++j)
      v[j] = (short)f2bf(sC[(mt * 16 + ln) * 289 + (q * 8 + j) * 9 + t]);
    *(s16x8*)&ob[(size_t)e * 8] = v;
  }
}

// ---------------------------------------------------------------------------
// Head weight prep: fp32 (81,256) -> bf16 A-frag order [kk][mt][lane][8].
// Rows 81..95 zero-padded.  3072 lane-frags total.
// NOTE: in the fast path this is launched AFTER the last bufA consumer —
// w3b lives inside the dead bufA region (round-2 bug: launching it first
// let tpose_k clobber it).
// ---------------------------------------------------------------------------
__global__ __launch_bounds__(256) void wprep3_k(const float* __restrict__ w3,
                                                unsigned short* __restrict__ w3b)
{
  const int tid = threadIdx.x + blockIdx.x * 256;
  if (tid >= 3072) return;
  const int kk = tid / 384, r = tid % 384;
  const int mt = r >> 6, lane = r & 63;
  const int ln = lane & 15, q = lane >> 4;
  const int co = mt * 16 + ln;
  s16x8 v;
  #pragma unroll
  for (int j = 0; j < 8; ++j)
    v[j] = (co < 81) ? (short)f2bf(w3[co * 256 + kk * 32 + q * 8 + j]) : (short)0;
  *(s16x8*)&w3b[(size_t)tid * 8] = v;
}

// ---------------------------------------------------------------------------
// 3x3 conv + bias + relu via MFMA bf16 implicit GEMM.
// ---------------------------------------------------------------------------
template <int SRC_BF16, int EPI_BF16>
__global__ __launch_bounds__(256, 3) void conv_mfma_k(
    const void* __restrict__ inp,
    const unsigned short* __restrict__ Wb,
    const float* __restrict__ bias,
    void* __restrict__ outp,
    int CC, int occ0, int outCC)
{
  __shared__ short sIn[6 * 66 * 32];   // 25344 B
  __shared__ short sW[9216];           // 18432 B

  const int tid = threadIdx.x;
  const int lane = tid & 63;
  const int wid = tid >> 6;
  const int ln = lane & 15;
  const int q = lane >> 4;
  const int w0 = wid * 16;
  const int pb = blockIdx.x;
  const int b = pb >> 4;
  const int h0 = (pb & 15) * 4;
  const int cob = blockIdx.y;

  if (tid < 48) {
    int r = tid >> 3, side = (tid >> 2) & 1, qq = tid & 3;
    int col = side ? 65 : 0;
    s16x8 z = (s16x8)0;
    *(s16x8*)&sIn[(r * 66 + col) * 32 + qq * 8] = z;
  }
  if (SRC_BF16) {
    #pragma unroll
    for (int r = 0; r < 6; ++r) {
      int h = h0 - 1 + r;
      if (h < 0 || h > 63) {
        s16x8 z = (s16x8)0;
        *(s16x8*)&sIn[(r * 66 + 1) * 32 + tid * 8] = z;
      }
    }
  }

  f32x4 acc[2][4];
  #pragma unroll
  for (int mt = 0; mt < 2; ++mt)
    #pragma unroll
    for (int r = 0; r < 4; ++r) acc[mt][r] = (f32x4){0.f, 0.f, 0.f, 0.f};

  for (int cc = 0; cc < CC; ++cc) {
    {
      const unsigned short* gw = Wb + (size_t)(cob * CC + cc) * 9216;
      for (int s = wid; s < 18; s += 4)
        async16(&sW[s * 512 + lane * 8], gw + s * 512 + lane * 8);
    }
    if (SRC_BF16) {
      const unsigned short* cat = (const unsigned short*)inp;
      #pragma unroll
      for (int k = 0; k < 6; ++k) {
        int h = h0 - 1 + k;
        if (h >= 0 && h <= 63) {
          const unsigned short* gsrc =
              cat + ((size_t)(b * 64 + h) * CC + cc) * 2048 + wid * 512 + lane * 8;
          async16(&sIn[(k * 66 + 1) * 32 + wid * 512 + lane * 8], gsrc);
        }
      }
    } else {
      const float* fin = (const float*)inp;
      const int sq = tid & 3, sw = tid >> 2;
      #pragma unroll
      for (int r = 0; r < 6; ++r) {
        int h = h0 - 1 + r;
        s16x8 v;
        if (h >= 0 && h <= 63) {
          #pragma unroll
          for (int k = 0; k < 8; ++k) {
            float val = fin[((size_t)(b * (CC * 32) + cc * 32 + sq * 8 + k) << 12) +
                            h * 64 + sw];
            v[k] = (short)f2bf(val);
          }
        } else {
          v = (s16x8)0;
        }
        *(s16x8*)&sIn[(r * 66 + sw + 1) * 32 + sq * 8] = v;
      }
    }
    __syncthreads();
    #pragma unroll
    for (int kw = 0; kw < 3; ++kw) {
      s16x8 Bfr[6];
      #pragma unroll
      for (int rp = 0; rp < 6; ++rp)
        Bfr[rp] = *(const s16x8*)&sIn[(rp * 66 + w0 + kw + ln) * 32 + q * 8];
      #pragma unroll
      for (int kh = 0; kh < 3; ++kh) {
        #pragma unroll
        for (int mt = 0; mt < 2; ++mt) {
          s16x8 Afr = *(const s16x8*)&sW[((kh * 3 + kw) * 2 + mt) * 512 + lane * 8];
          #pragma unroll
          for (int r = 0; r < 4; ++r)
            acc[mt][r] = __builtin_amdgcn_mfma_f32_16x16x32_bf16(
                Afr, Bfr[r + kh], acc[mt][r], 0, 0, 0);
        }
      }
    }
    __syncthreads();
  }

  #pragma unroll
  for (int mt = 0; mt < 2; ++mt) {
    const float4 bv = *(const float4*)&bias[cob * 32 + mt * 16 + q * 4];
    #pragma unroll
    for (int r = 0; r < 4; ++r) {
      float y0 = fmaxf(acc[mt][r].x + bv.x, 0.f);
      float y1 = fmaxf(acc[mt][r].y + bv.y, 0.f);
      float y2 = fmaxf(acc[mt][r].z + bv.z, 0.f);
      float y3 = fmaxf(acc[mt][r].w + bv.w, 0.f);
      if (EPI_BF16) {
        s16x4 pk;
        pk[0] = (short)f2bf(y0); pk[1] = (short)f2bf(y1);
        pk[2] = (short)f2bf(y2); pk[3] = (short)f2bf(y3);
        unsigned short* ob = (unsigned short*)outp;
        size_t off = ((size_t)(b * 64 + h0 + r) * outCC + (occ0 + cob)) * 2048 +
                     (w0 + ln) * 32 + mt * 16 + q * 4;
        *(s16x4*)&ob[off] = pk;
      } else {
        float* ob = (float*)outp;
        int co = cob * 32 + mt * 16 + q * 4;
        size_t base = ((size_t)b * outCC + co) * HW2 + (h0 + r) * 64 + w0 + ln;
        ob[base] = y0;
        ob[base + HW2] = y1;
        ob[base + 2 * HW2] = y2;
        ob[base + 3 * HW2] = y3;
      }
    }
  }
}

// ---------------------------------------------------------------------------
// 1x1 head (256->81) + bias + relu + softmax via MFMA.  Block = (b,h) row,
// 4 waves = 4 w-tiles of 16.  No LDS, no barriers.
// ---------------------------------------------------------------------------
__global__ __launch_bounds__(256) void head_mfma_k(
    const unsigned short* __restrict__ x2b, const unsigned short* __restrict__ w3b,
    const float* __restrict__ b3, float* __restrict__ kern)
{
  const int bh = blockIdx.x;
  const int b = bh >> 6, h = bh & 63;
  const int tid = threadIdx.x;
  const int lane = tid & 63;
  const int wid = tid >> 6;
  const int ln = lane & 15, q = lane >> 4;
  const int w0 = wid * 16;

  f32x4 acc[6];
  #pragma unroll
  for (int mt = 0; mt < 6; ++mt) acc[mt] = (f32x4){0.f, 0.f, 0.f, 0.f};

  const unsigned short* xrow = x2b + (size_t)(b * 64 + h) * 8 * 2048;
  #pragma unroll
  for (int kk = 0; kk < 8; ++kk) {
    s16x8 Bfr = *(const s16x8*)&xrow[kk * 2048 + (w0 + ln) * 32 + q * 8];
    #pragma unroll
    for (int mt = 0; mt < 6; ++mt) {
      s16x8 Afr = *(const s16x8*)&w3b[(size_t)((kk * 6 + mt) * 64 + lane) * 8];
      acc[mt] = __builtin_amdgcn_mfma_f32_16x16x32_bf16(Afr, Bfr, acc[mt], 0, 0, 0);
    }
  }

  // bias + relu (co = mt*16 + q*4 + r; valid co < 81)
  float vv[20];
  #pragma unroll
  for (int mt = 0; mt < 5; ++mt)
    #pragma unroll
    for (int r = 0; r < 4; ++r)
      vv[mt * 4 + r] = fmaxf(acc[mt][r] + b3[mt * 16 + q * 4 + r], 0.f);
  float v80 = fmaxf(acc[5][0] + b3[80], 0.f);   // valid only when q==0

  float m = vv[0];
  #pragma unroll
  for (int k = 1; k < 20; ++k) m = fmaxf(m, vv[k]);
  if (q == 0) m = fmaxf(m, v80);
  m = fmaxf(m, __shfl_xor(m, 16));
  m = fmaxf(m, __shfl_xor(m, 32));

  float e[20], e80 = 0.f, s = 0.f;
  #pragma unroll
  for (int k = 0; k < 20; ++k) { e[k] = __expf(vv[k] - m); s += e[k]; }
  if (q == 0) { e80 = __expf(v80 - m); s += e80; }
  s += __shfl_xor(s, 16);
  s += __shfl_xor(s, 32);
  const float rr = 1.f / s;

  float* kp = kern + (size_t)(b * 81) * HW2 + h * 64 + w0 + ln;
  #pragma unroll
  for (int mt = 0; mt < 5; ++mt)
    #pragma unroll
    for (int r = 0; r < 4; ++r)
      kp[(size_t)(mt * 16 + q * 4 + r) * HW2] = e[mt * 4 + r] * rr;
  if (q == 0) kp[(size_t)80 * HW2] = e80 * rr;
}

// ---------------------------------------------------------------------------
// Spatially-variant conv, v6: h-pair blocks for input-row reuse.
// Round-5 lesson: full sched fence -> 256 VGPR + spill.  Round-6 lesson:
// XCD swizzle cut FETCH (56->46MB) but NOT time -> stall is per-wave at-use
// load latency, not hit tier.  Fix the ratio instead: rows h,h+1 share 8/9
// input rows; one block computes both, so each loaded row feeds 2x144 FMAs
// (tap r for out0, tap r-1 for out1).  Loads/output drop 1.8x, FMA:load
// 11->22, same at-use schedule now covers latency ~2x better.
// Linear block mapping (swizzle reverted).  Grid (16, 32, 4).
// ---------------------------------------------------------------------------
__global__ __launch_bounds__(256) void svc_k6(
    const float* __restrict__ feats, const float* __restrict__ kern,
    float* __restrict__ out)
{
  __shared__ float sK[2][81 * 64];    // 41472 B -> 3 blocks/CU
  const int b = blockIdx.z, h0 = blockIdx.y * 2, cb = blockIdx.x * 64;
  const int tid = threadIdx.x;

  // stage kern rows h0 and h0+1 (float4); zero taps whose input row is OOB
  for (int e = tid; e < 2592; e += 256) {
    int row = e / 1296, rem = e % 1296;
    int tap = rem >> 4, w4 = (rem & 15) * 4;
    int i = tap / 9;
    int h = h0 + row;
    f32x4 v = {0.f, 0.f, 0.f, 0.f};
    if ((unsigned)(h - 4 + i) <= 63u)
      v = *(const f32x4*)&kern[((size_t)(b * 81) + tap) * HW2 + h * 64 + w4];
    *(f32x4*)&sK[row][tap * 64 + w4] = v;
  }

  const int wq = tid & 15, cs = tid >> 4;
  const int w0 = wq * 4;
  const i32x4 srd = make_srd(feats, 4u * 1024u * 4096u * 4u);

  // 32-bit byte offsets (OOB -> HW zero; garbage rows killed by zeroed taps)
  int ibase = (((b * 1024 + cb + cs * 4) << 12) + (h0 - 4) * 64 + w0) * 4;
  unsigned vL[4], vM[4], vR[4];
  #pragma unroll
  for (int ch = 0; ch < 4; ++ch) {
    unsigned m = (unsigned)(ibase + ch * (4096 * 4));
    vM[ch] = m;
    vL[ch] = wq ? (m - 16u) : 0xF0000000u;          // OOB sentinel -> zeros
    vR[ch] = (wq != 15) ? (m + 16u) : 0xF0000000u;  // OOB sentinel -> zeros
  }

  f32x4 acc0[4], acc1[4];
  #pragma unroll
  for (int ch = 0; ch < 4; ++ch) {
    acc0[ch] = (f32x4){0.f, 0.f, 0.f, 0.f};
    acc1[ch] = (f32x4){0.f, 0.f, 0.f, 0.f};
  }

  float fC[4][12], fN[4][12];
  // prologue: input row r=0 (= h0-4)
  #pragma unroll
  for (int ch = 0; ch < 4; ++ch) {
    f32x4 L = llvm_amdgcn_raw_buffer_load_v4f32(srd, (int)vL[ch], 0, 0);
    f32x4 M = llvm_amdgcn_raw_buffer_load_v4f32(srd, (int)vM[ch], 0, 0);
    f32x4 R = llvm_amdgcn_raw_buffer_load_v4f32(srd, (int)vR[ch], 0, 0);
    fC[ch][0] = L[0]; fC[ch][1] = L[1]; fC[ch][2]  = L[2]; fC[ch][3]  = L[3];
    fC[ch][4] = M[0]; fC[ch][5] = M[1]; fC[ch][6]  = M[2]; fC[ch][7]  = M[3];
    fC[ch][8] = R[0]; fC[ch][9] = R[1]; fC[ch][10] = R[2]; fC[ch][11] = R[3];
  }
  __syncthreads();

  // input rows r=0..9 (h0-4 .. h0+5): r<9 -> out0 tap r; r>=1 -> out1 tap r-1
  #pragma unroll
  for (int r = 0; r < 10; ++r) {
    if (r < 9) {
      #pragma unroll
      for (int ch = 0; ch < 4; ++ch) {
        const int ro = (r + 1) * 256;  // compile-time; folds into imm offset
        f32x4 L = llvm_amdgcn_raw_buffer_load_v4f32(srd, (int)(vL[ch] + ro), 0, 0);
        f32x4 M = llvm_amdgcn_raw_buffer_load_v4f32(srd, (int)(vM[ch] + ro), 0, 0);
        f32x4 R = llvm_amdgcn_raw_buffer_load_v4f32(srd, (int)(vR[ch] + ro), 0, 0);
        fN[ch][0] = L[0]; fN[ch][1] = L[1]; fN[ch][2]  = L[2]; fN[ch][3]  = L[3];
        fN[ch][4] = M[0]; fN[ch][5] = M[1]; fN[ch][6]  = M[2]; fN[ch][7]  = M[3];
        fN[ch][8] = R[0]; fN[ch][9] = R[1]; fN[ch][10] = R[2]; fN[ch][11] = R[3];
      }
    }
    #pragma unroll
    for (int j = 0; j < 9; ++j) {
      if (r < 9) {
        const f32x4 kv = *(const f32x4*)&sK[0][(r * 9 + j) * 64 + w0];
        #pragma unroll
        for (int ch = 0; ch < 4; ++ch) {
          acc0[ch][0] += fC[ch][j]     * kv[0];
          acc0[ch][1] += fC[ch][j + 1] * kv[1];
          acc0[ch][2] += fC[ch][j + 2] * kv[2];
          acc0[ch][3] += fC[ch][j + 3] * kv[3];
        }
      }
      if (r >= 1) {
        const f32x4 kv = *(const f32x4*)&sK[1][((r - 1) * 9 + j) * 64 + w0];
        #pragma unroll
        for (int ch = 0; ch < 4; ++ch) {
          acc1[ch][0] += fC[ch][j]     * kv[0];
          acc1[ch][1] += fC[ch][j + 1] * kv[1];
          acc1[ch][2] += fC[ch][j + 2] * kv[2];
          acc1[ch][3] += fC[ch][j + 3] * kv[3];
        }
      }
    }
    if (r < 9) {
      #pragma unroll
      for (int ch = 0; ch < 4; ++ch)
        #pragma unroll
        for (int t = 0; t < 12; ++t) fC[ch][t] = fN[ch][t];
    }
  }

  #pragma unroll
  for (int ch = 0; ch < 4; ++ch) {
    size_t base = ((size_t)(b * 1024 + cb + cs * 4 + ch)) * HW2 + h0 * 64 + w0;
    *(f32x4*)&out[base] = acc0[ch];
    *(f32x4*)&out[base + 64] = acc1[ch];
  }
}

// ---------------------------------------------------------------------------
extern "C" void kernel_launch(void* const* d_in, const int* in_sizes, int n_in,
                              void* d_out, int out_size, void* d_ws, size_t ws_size,
                              hipStream_t stream) {
  const float* cur  = (const float*)d_in[0];
  const float* keyl = (const float*)d_in[1];
  const float* keyh = (const float*)d_in[2];
  const float* w_r  = (const float*)d_in[3];
  const float* b_r  = (const float*)d_in[4];
  const float* w2   = (const float*)d_in[5];
  const float* b2   = (const float*)d_in[6];
  const float* w3   = (const float*)d_in[7];
  const float* b3   = (const float*)d_in[8];
  float* out = (float*)d_out;
  char* ws = (char*)d_ws;

  const size_t NEED_FAST = 57409536;
  if (ws_size >= NEED_FAST) {
    // fast path layout:
    //   cat 16.78MB | Wb1 4.72MB | Wb2 2.36MB | bufA 33.55MB [23855104,57409536)
    //   After the conv1 pair, bufA is dead; x2b [23855104,32243712),
    //   kern [40632320,45940736) and w3b [45940736,45989888) overlay it.
    //   wprep3_k MUST launch after the last bufA consumer (round-2 bug).
    unsigned short* cat  = (unsigned short*)ws;
    unsigned short* Wb1  = (unsigned short*)(ws + 16777216);
    unsigned short* Wb2  = (unsigned short*)(ws + 21495808);
    unsigned short* bufA = (unsigned short*)(ws + 23855104);
    unsigned short* x2b  = (unsigned short*)(ws + 23855104);
    float*          kern = (float*)(ws + 40632320);
    unsigned short* w3b  = (unsigned short*)(ws + 45940736);

    wprep_k<<<256, 256, 0, stream>>>(w_r, Wb1, 1024);
    wprep_k<<<128, 256, 0, stream>>>(w2,  Wb2, 512);

    tpose_k<<<dim3(32, 8, 4), 256, 0, stream>>>(cur, bufA, 32);
    conv_mfma_k<1, 1><<<dim3(64, 8), 256, 0, stream>>>(bufA, Wb1, b_r, cat, 32, 0, 16);
    tpose_k<<<dim3(32, 8, 4), 256, 0, stream>>>(keyl, bufA, 32);
    conv_mfma_k<1, 1><<<dim3(64, 8), 256, 0, stream>>>(bufA, Wb1, b_r, cat, 32, 8, 16);

    wprep3_k<<<12, 256, 0, stream>>>(w3, w3b);   // bufA dead from here on

    conv_mfma_k<1, 1><<<dim3(64, 8), 256, 0, stream>>>(cat, Wb2, b2, x2b, 16, 0, 8);

    head_mfma_k<<<256, 256, 0, stream>>>(x2b, w3b, b3, kern);
    svc_k6<<<dim3(16, 32, 4), 256, 0, stream>>>(keyh, kern, out);
  } else {
    // fallback (37.6MB): fp32-NCHW staged convs, same MFMA head (no overlap)
    unsigned short* cat  = (unsigned short*)ws;
    unsigned short* x2b  = (unsigned short*)(ws + 16777216);
    float*          kern = (float*)(ws + 25165824);
    unsigned short* Wb1  = (unsigned short*)(ws + 30474240);
    unsigned short* Wb2  = (unsigned short*)(ws + 35192832);
    unsigned short* w3b  = (unsigned short*)(ws + 37552128);

    wprep_k<<<256, 256, 0, stream>>>(w_r, Wb1, 1024);
    wprep_k<<<128, 256, 0, stream>>>(w2,  Wb2, 512);
    wprep3_k<<<12, 256, 0, stream>>>(w3, w3b);

    conv_mfma_k<0, 1><<<dim3(64, 8), 256, 0, stream>>>(cur,  Wb1, b_r, cat, 32, 0, 16);
    conv_mfma_k<0, 1><<<dim3(64, 8), 256, 0, stream>>>(keyl, Wb1, b_r, cat, 32, 8, 16);
    conv_mfma_k<1, 1><<<dim3(64, 8), 256, 0, stream>>>(cat,  Wb2, b2, x2b, 16, 0, 8);

    head_mfma_k<<<256, 256, 0, stream>>>(x2b, w3b, b3, kern);
    svc_k6<<<dim3(16, 32, 4), 256, 0, stream>>>(keyh, kern, out);
  }
}

// Round 9
// 760.971 us; speedup vs baseline: 1.4861x; 1.4861x over previous
//
#include <hip/hip_runtime.h>
#include <math.h>

#define HW2 4096

typedef __attribute__((ext_vector_type(8))) short s16x8;
typedef __attribute__((ext_vector_type(4))) short s16x4;
typedef __attribute__((ext_vector_type(4))) float f32x4;
typedef __attribute__((ext_vector_type(4))) int i32x4;

__device__ __forceinline__ unsigned short f2bf(float x) {
  unsigned int u = __float_as_uint(x);
  u += 0x7fff + ((u >> 16) & 1);          // RNE
  return (unsigned short)(u >> 16);
}

__device__ __forceinline__ void async16(void* lds, const void* g) {
  __builtin_amdgcn_global_load_lds(
      (const __attribute__((address_space(1))) void*)g,
      (__attribute__((address_space(3))) void*)lds, 16, 0, 0);
}

// ---------------------------------------------------------------------------
// fp32 NCHW -> bf16 transposed [b][h][cc][w*32+ci].  Block = (cc, h8, b).
// ---------------------------------------------------------------------------
__global__ __launch_bounds__(256) void tpose_k(
    const float* __restrict__ in, unsigned short* __restrict__ outT, int CC)
{
  __shared__ short sT[32 * 534];
  const int cc = blockIdx.x;
  const int h0 = blockIdx.y * 8;
  const int b  = blockIdx.z;
  const int tid = threadIdx.x;
  const float* ip = in + (size_t)(b * CC + cc) * 32 * 4096;

  for (int e = tid; e < 4096; e += 256) {
    int ci = e >> 7, rem = e & 127;
    int h = rem >> 4, w4 = rem & 15;
    float4 v = *(const float4*)&ip[(size_t)ci * 4096 + (h0 + h) * 64 + w4 * 4];
    short* d = &sT[ci * 534 + h * 66 + w4 * 4];
    d[0] = (short)f2bf(v.x); d[1] = (short)f2bf(v.y);
    d[2] = (short)f2bf(v.z); d[3] = (short)f2bf(v.w);
  }
  __syncthreads();
  unsigned short* ob = outT + (size_t)b * 64 * CC * 2048;
  for (int e = tid; e < 2048; e += 256) {
    int h = e >> 8, rem = e & 255;
    int w = rem >> 2, q = rem & 3;
    s16x8 v;
    #pragma unroll
    for (int j = 0; j < 8; ++j) v[j] = sT[(q * 8 + j) * 534 + h * 66 + w];
    *(s16x8*)&ob[((size_t)(h0 + h) * CC + cc) * 2048 + w * 32 + q * 8] = v;
  }
}

// ---------------------------------------------------------------------------
// Weight prep (coalesced): fp32 OIHW -> bf16 MFMA A-frag order.
// ---------------------------------------------------------------------------
__global__ __launch_bounds__(256) void wprep_k(const float* __restrict__ w,
                                               unsigned short* __restrict__ Wb,
                                               int Cin) {
  __shared__ float sC[32 * 289];
  const int CC = Cin >> 5;
  const int cc = blockIdx.x % CC, cob = blockIdx.x / CC;
  const int tid = threadIdx.x;
  for (int e = tid; e < 2304; e += 256) {
    int co = e / 72, off = e % 72;
    float4 v = *(const float4*)&w[((size_t)(cob * 32 + co) * Cin + cc * 32) * 9 +
                                  off * 4];
    float* d = &sC[co * 289 + off * 4];
    d[0] = v.x; d[1] = v.y; d[2] = v.z; d[3] = v.w;
  }
  __syncthreads();
  unsigned short* ob = Wb + (size_t)(cob * CC + cc) * 9216;
  for (int e = tid; e < 1152; e += 256) {
    int ln = e & 15, q = (e >> 4) & 3, mt = (e >> 6) & 1, t = e >> 7;
    s16x8 v;
    #pragma unroll
    for (int j = 0; j < 8; ++j)
      v[j] = (short)f2bf(sC[(mt * 16 + ln) * 289 + (q * 8 + j) * 9 + t]);
    *(s16x8*)&ob[(size_t)e * 8] = v;
  }
}

// ---------------------------------------------------------------------------
// Head weight prep: fp32 (81,256) -> bf16 A-frag order [kk][mt][lane][8].
// Rows 81..95 zero-padded.  3072 lane-frags total.
// NOTE: launched AFTER the last bufA consumer in the fast path (round-2 bug).
// ---------------------------------------------------------------------------
__global__ __launch_bounds__(256) void wprep3_k(const float* __restrict__ w3,
                                                unsigned short* __restrict__ w3b)
{
  const int tid = threadIdx.x + blockIdx.x * 256;
  if (tid >= 3072) return;
  const int kk = tid / 384, r = tid % 384;
  const int mt = r >> 6, lane = r & 63;
  const int ln = lane & 15, q = lane >> 4;
  const int co = mt * 16 + ln;
  s16x8 v;
  #pragma unroll
  for (int j = 0; j < 8; ++j)
    v[j] = (co < 81) ? (short)f2bf(w3[co * 256 + kk * 32 + q * 8 + j]) : (short)0;
  *(s16x8*)&w3b[(size_t)tid * 8] = v;
}

// ---------------------------------------------------------------------------
// 3x3 conv + bias + relu via MFMA bf16 implicit GEMM.
// ---------------------------------------------------------------------------
template <int SRC_BF16, int EPI_BF16>
__global__ __launch_bounds__(256, 3) void conv_mfma_k(
    const void* __restrict__ inp,
    const unsigned short* __restrict__ Wb,
    const float* __restrict__ bias,
    void* __restrict__ outp,
    int CC, int occ0, int outCC)
{
  __shared__ short sIn[6 * 66 * 32];   // 25344 B
  __shared__ short sW[9216];           // 18432 B

  const int tid = threadIdx.x;
  const int lane = tid & 63;
  const int wid = tid >> 6;
  const int ln = lane & 15;
  const int q = lane >> 4;
  const int w0 = wid * 16;
  const int pb = blockIdx.x;
  const int b = pb >> 4;
  const int h0 = (pb & 15) * 4;
  const int cob = blockIdx.y;

  if (tid < 48) {
    int r = tid >> 3, side = (tid >> 2) & 1, qq = tid & 3;
    int col = side ? 65 : 0;
    s16x8 z = (s16x8)0;
    *(s16x8*)&sIn[(r * 66 + col) * 32 + qq * 8] = z;
  }
  if (SRC_BF16) {
    #pragma unroll
    for (int r = 0; r < 6; ++r) {
      int h = h0 - 1 + r;
      if (h < 0 || h > 63) {
        s16x8 z = (s16x8)0;
        *(s16x8*)&sIn[(r * 66 + 1) * 32 + tid * 8] = z;
      }
    }
  }

  f32x4 acc[2][4];
  #pragma unroll
  for (int mt = 0; mt < 2; ++mt)
    #pragma unroll
    for (int r = 0; r < 4; ++r) acc[mt][r] = (f32x4){0.f, 0.f, 0.f, 0.f};

  for (int cc = 0; cc < CC; ++cc) {
    {
      const unsigned short* gw = Wb + (size_t)(cob * CC + cc) * 9216;
      for (int s = wid; s < 18; s += 4)
        async16(&sW[s * 512 + lane * 8], gw + s * 512 + lane * 8);
    }
    if (SRC_BF16) {
      const unsigned short* cat = (const unsigned short*)inp;
      #pragma unroll
      for (int k = 0; k < 6; ++k) {
        int h = h0 - 1 + k;
        if (h >= 0 && h <= 63) {
          const unsigned short* gsrc =
              cat + ((size_t)(b * 64 + h) * CC + cc) * 2048 + wid * 512 + lane * 8;
          async16(&sIn[(k * 66 + 1) * 32 + wid * 512 + lane * 8], gsrc);
        }
      }
    } else {
      const float* fin = (const float*)inp;
      const int sq = tid & 3, sw = tid >> 2;
      #pragma unroll
      for (int r = 0; r < 6; ++r) {
        int h = h0 - 1 + r;
        s16x8 v;
        if (h >= 0 && h <= 63) {
          #pragma unroll
          for (int k = 0; k < 8; ++k) {
            float val = fin[((size_t)(b * (CC * 32) + cc * 32 + sq * 8 + k) << 12) +
                            h * 64 + sw];
            v[k] = (short)f2bf(val);
          }
        } else {
          v = (s16x8)0;
        }
        *(s16x8*)&sIn[(r * 66 + sw + 1) * 32 + sq * 8] = v;
      }
    }
    __syncthreads();
    #pragma unroll
    for (int kw = 0; kw < 3; ++kw) {
      s16x8 Bfr[6];
      #pragma unroll
      for (int rp = 0; rp < 6; ++rp)
        Bfr[rp] = *(const s16x8*)&sIn[(rp * 66 + w0 + kw + ln) * 32 + q * 8];
      #pragma unroll
      for (int kh = 0; kh < 3; ++kh) {
        #pragma unroll
        for (int mt = 0; mt < 2; ++mt) {
          s16x8 Afr = *(const s16x8*)&sW[((kh * 3 + kw) * 2 + mt) * 512 + lane * 8];
          #pragma unroll
          for (int r = 0; r < 4; ++r)
            acc[mt][r] = __builtin_amdgcn_mfma_f32_16x16x32_bf16(
                Afr, Bfr[r + kh], acc[mt][r], 0, 0, 0);
        }
      }
    }
    __syncthreads();
  }

  #pragma unroll
  for (int mt = 0; mt < 2; ++mt) {
    const float4 bv = *(const float4*)&bias[cob * 32 + mt * 16 + q * 4];
    #pragma unroll
    for (int r = 0; r < 4; ++r) {
      float y0 = fmaxf(acc[mt][r].x + bv.x, 0.f);
      float y1 = fmaxf(acc[mt][r].y + bv.y, 0.f);
      float y2 = fmaxf(acc[mt][r].z + bv.z, 0.f);
      float y3 = fmaxf(acc[mt][r].w + bv.w, 0.f);
      if (EPI_BF16) {
        s16x4 pk;
        pk[0] = (short)f2bf(y0); pk[1] = (short)f2bf(y1);
        pk[2] = (short)f2bf(y2); pk[3] = (short)f2bf(y3);
        unsigned short* ob = (unsigned short*)outp;
        size_t off = ((size_t)(b * 64 + h0 + r) * outCC + (occ0 + cob)) * 2048 +
                     (w0 + ln) * 32 + mt * 16 + q * 4;
        *(s16x4*)&ob[off] = pk;
      } else {
        float* ob = (float*)outp;
        int co = cob * 32 + mt * 16 + q * 4;
        size_t base = ((size_t)b * outCC + co) * HW2 + (h0 + r) * 64 + w0 + ln;
        ob[base] = y0;
        ob[base + HW2] = y1;
        ob[base + 2 * HW2] = y2;
        ob[base + 3 * HW2] = y3;
      }
    }
  }
}

// ---------------------------------------------------------------------------
// 1x1 head (256->81) + bias + relu + softmax via MFMA.  Block = (b,h) row,
// 4 waves = 4 w-tiles of 16.  No LDS, no barriers.
// ---------------------------------------------------------------------------
__global__ __launch_bounds__(256) void head_mfma_k(
    const unsigned short* __restrict__ x2b, const unsigned short* __restrict__ w3b,
    const float* __restrict__ b3, float* __restrict__ kern)
{
  const int bh = blockIdx.x;
  const int b = bh >> 6, h = bh & 63;
  const int tid = threadIdx.x;
  const int lane = tid & 63;
  const int wid = tid >> 6;
  const int ln = lane & 15, q = lane >> 4;
  const int w0 = wid * 16;

  f32x4 acc[6];
  #pragma unroll
  for (int mt = 0; mt < 6; ++mt) acc[mt] = (f32x4){0.f, 0.f, 0.f, 0.f};

  const unsigned short* xrow = x2b + (size_t)(b * 64 + h) * 8 * 2048;
  #pragma unroll
  for (int kk = 0; kk < 8; ++kk) {
    s16x8 Bfr = *(const s16x8*)&xrow[kk * 2048 + (w0 + ln) * 32 + q * 8];
    #pragma unroll
    for (int mt = 0; mt < 6; ++mt) {
      s16x8 Afr = *(const s16x8*)&w3b[(size_t)((kk * 6 + mt) * 64 + lane) * 8];
      acc[mt] = __builtin_amdgcn_mfma_f32_16x16x32_bf16(Afr, Bfr, acc[mt], 0, 0, 0);
    }
  }

  // bias + relu (co = mt*16 + q*4 + r; valid co < 81)
  float vv[20];
  #pragma unroll
  for (int mt = 0; mt < 5; ++mt)
    #pragma unroll
    for (int r = 0; r < 4; ++r)
      vv[mt * 4 + r] = fmaxf(acc[mt][r] + b3[mt * 16 + q * 4 + r], 0.f);
  float v80 = fmaxf(acc[5][0] + b3[80], 0.f);   // valid only when q==0

  float m = vv[0];
  #pragma unroll
  for (int k = 1; k < 20; ++k) m = fmaxf(m, vv[k]);
  if (q == 0) m = fmaxf(m, v80);
  m = fmaxf(m, __shfl_xor(m, 16));
  m = fmaxf(m, __shfl_xor(m, 32));

  float e[20], e80 = 0.f, s = 0.f;
  #pragma unroll
  for (int k = 0; k < 20; ++k) { e[k] = __expf(vv[k] - m); s += e[k]; }
  if (q == 0) { e80 = __expf(v80 - m); s += e80; }
  s += __shfl_xor(s, 16);
  s += __shfl_xor(s, 32);
  const float rr = 1.f / s;

  float* kp = kern + (size_t)(b * 81) * HW2 + h * 64 + w0 + ln;
  #pragma unroll
  for (int mt = 0; mt < 5; ++mt)
    #pragma unroll
    for (int r = 0; r < 4; ++r)
      kp[(size_t)(mt * 16 + q * 4 + r) * HW2] = e[mt * 4 + r] * rr;
  if (q == 0) kp[(size_t)80 * HW2] = e80 * rr;
}

// ---------------------------------------------------------------------------
// Spatially-variant conv, v7: LDS-staged row pipeline (conv_mfma pattern).
// Round 5+7 lesson: register pipelines (fence / h-pair) blow regalloc to
// 256 VGPR + GB-scale scratch.  Put the pipeline in LDS instead:
//  - a block's L/M/R taps live in ONE 64ch x 64w input row = 16KB, staged
//    with 4 async16/thread into linear [ch][64] (wave-uniform+lane*16 OK);
//  - w-edge zeros via a 16B zero scratch selected by i-invariant read addrs;
//  - OOB rows: not staged; sK taps zeroed (h<4 blocks zero-init sF once —
//    race-free because they skip stage(0));
//  - per i: bar -> 12 ds_read_b128 -> bar -> stage(i+1) -> 144 FMA.
// LDS 37.1KB -> 4 blocks/CU (16 waves/CU TLP hides stage latency).
// ---------------------------------------------------------------------------
__global__ __launch_bounds__(256) void svc_k7(
    const float* __restrict__ feats, const float* __restrict__ kern,
    float* __restrict__ out)
{
  __shared__ float sK[81 * 64];                    // 20736 B
  __shared__ __align__(16) float sF[64 * 64 + 4];  // 16400 B (last 4 = zeros)
  const int b = blockIdx.z, h = blockIdx.y, cb = blockIdx.x * 64;
  const int tid = threadIdx.x;

  // zero scratch; full zero-init only for h<4 (those blocks skip stage(0),
  // so no ds_write vs async16 race)
  if (tid == 0) *(f32x4*)&sF[4096] = (f32x4){0.f, 0.f, 0.f, 0.f};
  if (h < 4) {
    for (int e = tid; e < 1024; e += 256)
      ((f32x4*)sF)[e] = (f32x4){0.f, 0.f, 0.f, 0.f};
  }

  // stage 81x64 kernel block; zero taps whose input row is OOB
  for (int e = tid; e < 81 * 16; e += 256) {
    int tap = e >> 4, w4 = (e & 15) * 4;
    int i = tap / 9;
    f32x4 v = {0.f, 0.f, 0.f, 0.f};
    if ((unsigned)(h - 4 + i) <= 63u)
      v = *(const f32x4*)&kern[((size_t)(b * 81) + tap) * HW2 + h * 64 + w4];
    *(f32x4*)&sK[tap * 64 + w4] = v;
  }

  const int wq = tid & 15, cs = tid >> 4;
  const int w0 = wq * 4;

  // i-invariant LDS read addresses (float indices); edge lanes -> zero scratch
  int aL[4], aM[4], aR[4];
  #pragma unroll
  for (int ch = 0; ch < 4; ++ch) {
    int base = (cs * 4 + ch) * 64 + w0;
    aM[ch] = base;
    aL[ch] = wq ? (base - 4) : 4096;
    aR[ch] = (wq != 15) ? (base + 4) : 4096;
  }

  // stage row i=0 (hh = h-4) if valid
  {
    int hh = h - 4;
    if (hh >= 0) {   // h<4 handled by zero-init; hh<=63 always here
      #pragma unroll
      for (int s = 0; s < 4; ++s) {
        int chunk = s * 256 + tid;
        int ch = chunk >> 4;
        async16((char*)sF + (size_t)chunk * 16,
                feats + (((size_t)(b * 1024 + cb + ch)) << 12) + hh * 64 +
                    (chunk & 15) * 4);
      }
    }
  }

  f32x4 acc[4];
  #pragma unroll
  for (int ch = 0; ch < 4; ++ch) acc[ch] = (f32x4){0.f, 0.f, 0.f, 0.f};

  #pragma unroll
  for (int i = 0; i < 9; ++i) {
    __syncthreads();   // stage(i) + sK (first iter) visible
    float f[4][12];
    #pragma unroll
    for (int ch = 0; ch < 4; ++ch) {
      f32x4 L = *(const f32x4*)&sF[aL[ch]];
      f32x4 M = *(const f32x4*)&sF[aM[ch]];
      f32x4 R = *(const f32x4*)&sF[aR[ch]];
      f[ch][0] = L[0]; f[ch][1] = L[1]; f[ch][2]  = L[2]; f[ch][3]  = L[3];
      f[ch][4] = M[0]; f[ch][5] = M[1]; f[ch][6]  = M[2]; f[ch][7]  = M[3];
      f[ch][8] = R[0]; f[ch][9] = R[1]; f[ch][10] = R[2]; f[ch][11] = R[3];
    }
    __syncthreads();   // reads done; safe to overwrite sF
    if (i < 8) {
      int hh = h - 4 + i + 1;
      if ((unsigned)hh <= 63u) {
        #pragma unroll
        for (int s = 0; s < 4; ++s) {
          int chunk = s * 256 + tid;
          int ch = chunk >> 4;
          async16((char*)sF + (size_t)chunk * 16,
                  feats + (((size_t)(b * 1024 + cb + ch)) << 12) + hh * 64 +
                      (chunk & 15) * 4);
        }
      }
    }
    #pragma unroll
    for (int j = 0; j < 9; ++j) {
      const f32x4 kv = *(const f32x4*)&sK[(i * 9 + j) * 64 + w0];
      #pragma unroll
      for (int ch = 0; ch < 4; ++ch) {
        acc[ch][0] += f[ch][j]     * kv[0];
        acc[ch][1] += f[ch][j + 1] * kv[1];
        acc[ch][2] += f[ch][j + 2] * kv[2];
        acc[ch][3] += f[ch][j + 3] * kv[3];
      }
    }
  }

  #pragma unroll
  for (int ch = 0; ch < 4; ++ch)
    *(f32x4*)&out[((size_t)(b * 1024 + cb + cs * 4 + ch)) * HW2 + h * 64 + w0] =
        acc[ch];
}

// ---------------------------------------------------------------------------
extern "C" void kernel_launch(void* const* d_in, const int* in_sizes, int n_in,
                              void* d_out, int out_size, void* d_ws, size_t ws_size,
                              hipStream_t stream) {
  const float* cur  = (const float*)d_in[0];
  const float* keyl = (const float*)d_in[1];
  const float* keyh = (const float*)d_in[2];
  const float* w_r  = (const float*)d_in[3];
  const float* b_r  = (const float*)d_in[4];
  const float* w2   = (const float*)d_in[5];
  const float* b2   = (const float*)d_in[6];
  const float* w3   = (const float*)d_in[7];
  const float* b3   = (const float*)d_in[8];
  float* out = (float*)d_out;
  char* ws = (char*)d_ws;

  const size_t NEED_FAST = 57409536;
  if (ws_size >= NEED_FAST) {
    // fast path layout:
    //   cat 16.78MB | Wb1 4.72MB | Wb2 2.36MB | bufA 33.55MB [23855104,57409536)
    //   After the conv1 pair, bufA is dead; x2b [23855104,32243712),
    //   kern [40632320,45940736) and w3b [45940736,45989888) overlay it.
    //   wprep3_k MUST launch after the last bufA consumer (round-2 bug).
    unsigned short* cat  = (unsigned short*)ws;
    unsigned short* Wb1  = (unsigned short*)(ws + 16777216);
    unsigned short* Wb2  = (unsigned short*)(ws + 21495808);
    unsigned short* bufA = (unsigned short*)(ws + 23855104);
    unsigned short* x2b  = (unsigned short*)(ws + 23855104);
    float*          kern = (float*)(ws + 40632320);
    unsigned short* w3b  = (unsigned short*)(ws + 45940736);

    wprep_k<<<256, 256, 0, stream>>>(w_r, Wb1, 1024);
    wprep_k<<<128, 256, 0, stream>>>(w2,  Wb2, 512);

    tpose_k<<<dim3(32, 8, 4), 256, 0, stream>>>(cur, bufA, 32);
    conv_mfma_k<1, 1><<<dim3(64, 8), 256, 0, stream>>>(bufA, Wb1, b_r, cat, 32, 0, 16);
    tpose_k<<<dim3(32, 8, 4), 256, 0, stream>>>(keyl, bufA, 32);
    conv_mfma_k<1, 1><<<dim3(64, 8), 256, 0, stream>>>(bufA, Wb1, b_r, cat, 32, 8, 16);

    wprep3_k<<<12, 256, 0, stream>>>(w3, w3b);   // bufA dead from here on

    conv_mfma_k<1, 1><<<dim3(64, 8), 256, 0, stream>>>(cat, Wb2, b2, x2b, 16, 0, 8);

    head_mfma_k<<<256, 256, 0, stream>>>(x2b, w3b, b3, kern);
    svc_k7<<<dim3(16, 64, 4), 256, 0, stream>>>(keyh, kern, out);
  } else {
    // fallback (37.6MB): fp32-NCHW staged convs, same MFMA head (no overlap)
    unsigned short* cat  = (unsigned short*)ws;
    unsigned short* x2b  = (unsigned short*)(ws + 16777216);
    float*          kern = (float*)(ws + 25165824);
    unsigned short* Wb1  = (unsigned short*)(ws + 30474240);
    unsigned short* Wb2  = (unsigned short*)(ws + 35192832);
    unsigned short* w3b  = (unsigned short*)(ws + 37552128);

    wprep_k<<<256, 256, 0, stream>>>(w_r, Wb1, 1024);
    wprep_k<<<128, 256, 0, stream>>>(w2,  Wb2, 512);
    wprep3_k<<<12, 256, 0, stream>>>(w3, w3b);

    conv_mfma_k<0, 1><<<dim3(64, 8), 256, 0, stream>>>(cur,  Wb1, b_r, cat, 32, 0, 16);
    conv_mfma_k<0, 1><<<dim3(64, 8), 256, 0, stream>>>(keyl, Wb1, b_r, cat, 32, 8, 16);
    conv_mfma_k<1, 1><<<dim3(64, 8), 256, 0, stream>>>(cat,  Wb2, b2, x2b, 16, 0, 8);

    head_mfma_k<<<256, 256, 0, stream>>>(x2b, w3b, b3, kern);
    svc_k7<<<dim3(16, 64, 4), 256, 0, stream>>>(keyh, kern, out);
  }
}

// Round 11
// 452.314 us; speedup vs baseline: 2.5003x; 1.6824x over previous
//
#include <hip/hip_runtime.h>
#include <math.h>

#define HW2 4096

typedef __attribute__((ext_vector_type(8))) short s16x8;
typedef __attribute__((ext_vector_type(4))) short s16x4;
typedef __attribute__((ext_vector_type(4))) float f32x4;
typedef __attribute__((ext_vector_type(4))) int i32x4;

__device__ __forceinline__ unsigned short f2bf(float x) {
  unsigned int u = __float_as_uint(x);
  u += 0x7fff + ((u >> 16) & 1);          // RNE
  return (unsigned short)(u >> 16);
}

__device__ __forceinline__ void async16(void* lds, const void* g) {
  __builtin_amdgcn_global_load_lds(
      (const __attribute__((address_space(1))) void*)g,
      (__attribute__((address_space(3))) void*)lds, 16, 0, 0);
}

// ---------------------------------------------------------------------------
// fp32 NCHW -> bf16 transposed [b][h][cc][w*32+ci].  Block = (cc, h8, b).
// ---------------------------------------------------------------------------
__global__ __launch_bounds__(256) void tpose_k(
    const float* __restrict__ in, unsigned short* __restrict__ outT, int CC)
{
  __shared__ short sT[32 * 534];
  const int cc = blockIdx.x;
  const int h0 = blockIdx.y * 8;
  const int b  = blockIdx.z;
  const int tid = threadIdx.x;
  const float* ip = in + (size_t)(b * CC + cc) * 32 * 4096;

  for (int e = tid; e < 4096; e += 256) {
    int ci = e >> 7, rem = e & 127;
    int h = rem >> 4, w4 = rem & 15;
    float4 v = *(const float4*)&ip[(size_t)ci * 4096 + (h0 + h) * 64 + w4 * 4];
    short* d = &sT[ci * 534 + h * 66 + w4 * 4];
    d[0] = (short)f2bf(v.x); d[1] = (short)f2bf(v.y);
    d[2] = (short)f2bf(v.z); d[3] = (short)f2bf(v.w);
  }
  __syncthreads();
  unsigned short* ob = outT + (size_t)b * 64 * CC * 2048;
  for (int e = tid; e < 2048; e += 256) {
    int h = e >> 8, rem = e & 255;
    int w = rem >> 2, q = rem & 3;
    s16x8 v;
    #pragma unroll
    for (int j = 0; j < 8; ++j) v[j] = sT[(q * 8 + j) * 534 + h * 66 + w];
    *(s16x8*)&ob[((size_t)(h0 + h) * CC + cc) * 2048 + w * 32 + q * 8] = v;
  }
}

// ---------------------------------------------------------------------------
// Weight prep (coalesced): fp32 OIHW -> bf16 MFMA A-frag order.
// ---------------------------------------------------------------------------
__global__ __launch_bounds__(256) void wprep_k(const float* __restrict__ w,
                                               unsigned short* __restrict__ Wb,
                                               int Cin) {
  __shared__ float sC[32 * 289];
  const int CC = Cin >> 5;
  const int cc = blockIdx.x % CC, cob = blockIdx.x / CC;
  const int tid = threadIdx.x;
  for (int e = tid; e < 2304; e += 256) {
    int co = e / 72, off = e % 72;
    float4 v = *(const float4*)&w[((size_t)(cob * 32 + co) * Cin + cc * 32) * 9 +
                                  off * 4];
    float* d = &sC[co * 289 + off * 4];
    d[0] = v.x; d[1] = v.y; d[2] = v.z; d[3] = v.w;
  }
  __syncthreads();
  unsigned short* ob = Wb + (size_t)(cob * CC + cc) * 9216;
  for (int e = tid; e < 1152; e += 256) {
    int ln = e & 15, q = (e >> 4) & 3, mt = (e >> 6) & 1, t = e >> 7;
    s16x8 v;
    #pragma unroll
    for (int j = 0; j < 8; ++j)
      v[j] = (short)f2bf(sC[(mt * 16 + ln) * 289 + (q * 8 + j) * 9 + t]);
    *(s16x8*)&ob[(size_t)e * 8] = v;
  }
}

// ---------------------------------------------------------------------------
// Head weight prep: fp32 (81,256) -> bf16 A-frag order [kk][mt][lane][8].
// Rows 81..95 zero-padded.  3072 lane-frags total.
// NOTE: launched AFTER the last bufA consumer in the fast path (round-2 bug).
// ---------------------------------------------------------------------------
__global__ __launch_bounds__(256) void wprep3_k(const float* __restrict__ w3,
                                                unsigned short* __restrict__ w3b)
{
  const int tid = threadIdx.x + blockIdx.x * 256;
  if (tid >= 3072) return;
  const int kk = tid / 384, r = tid % 384;
  const int mt = r >> 6, lane = r & 63;
  const int ln = lane & 15, q = lane >> 4;
  const int co = mt * 16 + ln;
  s16x8 v;
  #pragma unroll
  for (int j = 0; j < 8; ++j)
    v[j] = (co < 81) ? (short)f2bf(w3[co * 256 + kk * 32 + q * 8 + j]) : (short)0;
  *(s16x8*)&w3b[(size_t)tid * 8] = v;
}

// ---------------------------------------------------------------------------
// 3x3 conv + bias + relu via MFMA bf16 implicit GEMM.
// ---------------------------------------------------------------------------
template <int SRC_BF16, int EPI_BF16>
__global__ __launch_bounds__(256, 3) void conv_mfma_k(
    const void* __restrict__ inp,
    const unsigned short* __restrict__ Wb,
    const float* __restrict__ bias,
    void* __restrict__ outp,
    int CC, int occ0, int outCC)
{
  __shared__ short sIn[6 * 66 * 32];   // 25344 B
  __shared__ short sW[9216];           // 18432 B

  const int tid = threadIdx.x;
  const int lane = tid & 63;
  const int wid = tid >> 6;
  const int ln = lane & 15;
  const int q = lane >> 4;
  const int w0 = wid * 16;
  const int pb = blockIdx.x;
  const int b = pb >> 4;
  const int h0 = (pb & 15) * 4;
  const int cob = blockIdx.y;

  if (tid < 48) {
    int r = tid >> 3, side = (tid >> 2) & 1, qq = tid & 3;
    int col = side ? 65 : 0;
    s16x8 z = (s16x8)0;
    *(s16x8*)&sIn[(r * 66 + col) * 32 + qq * 8] = z;
  }
  if (SRC_BF16) {
    #pragma unroll
    for (int r = 0; r < 6; ++r) {
      int h = h0 - 1 + r;
      if (h < 0 || h > 63) {
        s16x8 z = (s16x8)0;
        *(s16x8*)&sIn[(r * 66 + 1) * 32 + tid * 8] = z;
      }
    }
  }

  f32x4 acc[2][4];
  #pragma unroll
  for (int mt = 0; mt < 2; ++mt)
    #pragma unroll
    for (int r = 0; r < 4; ++r) acc[mt][r] = (f32x4){0.f, 0.f, 0.f, 0.f};

  for (int cc = 0; cc < CC; ++cc) {
    {
      const unsigned short* gw = Wb + (size_t)(cob * CC + cc) * 9216;
      for (int s = wid; s < 18; s += 4)
        async16(&sW[s * 512 + lane * 8], gw + s * 512 + lane * 8);
    }
    if (SRC_BF16) {
      const unsigned short* cat = (const unsigned short*)inp;
      #pragma unroll
      for (int k = 0; k < 6; ++k) {
        int h = h0 - 1 + k;
        if (h >= 0 && h <= 63) {
          const unsigned short* gsrc =
              cat + ((size_t)(b * 64 + h) * CC + cc) * 2048 + wid * 512 + lane * 8;
          async16(&sIn[(k * 66 + 1) * 32 + wid * 512 + lane * 8], gsrc);
        }
      }
    } else {
      const float* fin = (const float*)inp;
      const int sq = tid & 3, sw = tid >> 2;
      #pragma unroll
      for (int r = 0; r < 6; ++r) {
        int h = h0 - 1 + r;
        s16x8 v;
        if (h >= 0 && h <= 63) {
          #pragma unroll
          for (int k = 0; k < 8; ++k) {
            float val = fin[((size_t)(b * (CC * 32) + cc * 32 + sq * 8 + k) << 12) +
                            h * 64 + sw];
            v[k] = (short)f2bf(val);
          }
        } else {
          v = (s16x8)0;
        }
        *(s16x8*)&sIn[(r * 66 + sw + 1) * 32 + sq * 8] = v;
      }
    }
    __syncthreads();
    #pragma unroll
    for (int kw = 0; kw < 3; ++kw) {
      s16x8 Bfr[6];
      #pragma unroll
      for (int rp = 0; rp < 6; ++rp)
        Bfr[rp] = *(const s16x8*)&sIn[(rp * 66 + w0 + kw + ln) * 32 + q * 8];
      #pragma unroll
      for (int kh = 0; kh < 3; ++kh) {
        #pragma unroll
        for (int mt = 0; mt < 2; ++mt) {
          s16x8 Afr = *(const s16x8*)&sW[((kh * 3 + kw) * 2 + mt) * 512 + lane * 8];
          #pragma unroll
          for (int r = 0; r < 4; ++r)
            acc[mt][r] = __builtin_amdgcn_mfma_f32_16x16x32_bf16(
                Afr, Bfr[r + kh], acc[mt][r], 0, 0, 0);
        }
      }
    }
    __syncthreads();
  }

  #pragma unroll
  for (int mt = 0; mt < 2; ++mt) {
    const float4 bv = *(const float4*)&bias[cob * 32 + mt * 16 + q * 4];
    #pragma unroll
    for (int r = 0; r < 4; ++r) {
      float y0 = fmaxf(acc[mt][r].x + bv.x, 0.f);
      float y1 = fmaxf(acc[mt][r].y + bv.y, 0.f);
      float y2 = fmaxf(acc[mt][r].z + bv.z, 0.f);
      float y3 = fmaxf(acc[mt][r].w + bv.w, 0.f);
      if (EPI_BF16) {
        s16x4 pk;
        pk[0] = (short)f2bf(y0); pk[1] = (short)f2bf(y1);
        pk[2] = (short)f2bf(y2); pk[3] = (short)f2bf(y3);
        unsigned short* ob = (unsigned short*)outp;
        size_t off = ((size_t)(b * 64 + h0 + r) * outCC + (occ0 + cob)) * 2048 +
                     (w0 + ln) * 32 + mt * 16 + q * 4;
        *(s16x4*)&ob[off] = pk;
      } else {
        float* ob = (float*)outp;
        int co = cob * 32 + mt * 16 + q * 4;
        size_t base = ((size_t)b * outCC + co) * HW2 + (h0 + r) * 64 + w0 + ln;
        ob[base] = y0;
        ob[base + HW2] = y1;
        ob[base + 2 * HW2] = y2;
        ob[base + 3 * HW2] = y3;
      }
    }
  }
}

// ---------------------------------------------------------------------------
// 1x1 head (256->81) + bias + relu + softmax via MFMA.  Block = (b,h) row,
// 4 waves = 4 w-tiles of 16.  No LDS, no barriers.
// ---------------------------------------------------------------------------
__global__ __launch_bounds__(256) void head_mfma_k(
    const unsigned short* __restrict__ x2b, const unsigned short* __restrict__ w3b,
    const float* __restrict__ b3, float* __restrict__ kern)
{
  const int bh = blockIdx.x;
  const int b = bh >> 6, h = bh & 63;
  const int tid = threadIdx.x;
  const int lane = tid & 63;
  const int wid = tid >> 6;
  const int ln = lane & 15, q = lane >> 4;
  const int w0 = wid * 16;

  f32x4 acc[6];
  #pragma unroll
  for (int mt = 0; mt < 6; ++mt) acc[mt] = (f32x4){0.f, 0.f, 0.f, 0.f};

  const unsigned short* xrow = x2b + (size_t)(b * 64 + h) * 8 * 2048;
  #pragma unroll
  for (int kk = 0; kk < 8; ++kk) {
    s16x8 Bfr = *(const s16x8*)&xrow[kk * 2048 + (w0 + ln) * 32 + q * 8];
    #pragma unroll
    for (int mt = 0; mt < 6; ++mt) {
      s16x8 Afr = *(const s16x8*)&w3b[(size_t)((kk * 6 + mt) * 64 + lane) * 8];
      acc[mt] = __builtin_amdgcn_mfma_f32_16x16x32_bf16(Afr, Bfr, acc[mt], 0, 0, 0);
    }
  }

  // bias + relu (co = mt*16 + q*4 + r; valid co < 81)
  float vv[20];
  #pragma unroll
  for (int mt = 0; mt < 5; ++mt)
    #pragma unroll
    for (int r = 0; r < 4; ++r)
      vv[mt * 4 + r] = fmaxf(acc[mt][r] + b3[mt * 16 + q * 4 + r], 0.f);
  float v80 = fmaxf(acc[5][0] + b3[80], 0.f);   // valid only when q==0

  float m = vv[0];
  #pragma unroll
  for (int k = 1; k < 20; ++k) m = fmaxf(m, vv[k]);
  if (q == 0) m = fmaxf(m, v80);
  m = fmaxf(m, __shfl_xor(m, 16));
  m = fmaxf(m, __shfl_xor(m, 32));

  float e[20], e80 = 0.f, s = 0.f;
  #pragma unroll
  for (int k = 0; k < 20; ++k) { e[k] = __expf(vv[k] - m); s += e[k]; }
  if (q == 0) { e80 = __expf(v80 - m); s += e80; }
  s += __shfl_xor(s, 16);
  s += __shfl_xor(s, 32);
  const float rr = 1.f / s;

  float* kp = kern + (size_t)(b * 81) * HW2 + h * 64 + w0 + ln;
  #pragma unroll
  for (int mt = 0; mt < 5; ++mt)
    #pragma unroll
    for (int r = 0; r < 4; ++r)
      kp[(size_t)(mt * 16 + q * 4 + r) * HW2] = e[mt * 4 + r] * rr;
  if (q == 0) kp[(size_t)80 * HW2] = e80 * rr;
}

// ---------------------------------------------------------------------------
// Spatially-variant conv, v8b: LDS row pipeline + ROLLED i-loop.
// Round-10 crash post-mortem: the k8 "simplified" stage source used
// (s*64)*4096 — 64 channels per s instead of 16 (chunk>>4 = s*16 + tid>>4)
// — reading up to ~9MB past feats for cb=960 -> GPU memory fault.
// Fixed: s advances 16 channels = s*65536 floats.  Dest unchanged
// (chunk*16 bytes).  Rolled-loop rationale (round 5/7/9 forensics): fully
// unrolled i-loops let the scheduler interleave register-only FMA blocks
// across iterations -> 256 VGPR + GB-scale scratch; #pragma unroll 1 makes
// cross-iteration mixing impossible (conv_mfma_k's rolled cc-loop pattern).
// Body per iter: bar -> 12 ds_read_b128 -> bar -> 4 async16(i+1) -> 144 FMA.
// ---------------------------------------------------------------------------
__global__ __launch_bounds__(256) void svc_k8(
    const float* __restrict__ feats, const float* __restrict__ kern,
    float* __restrict__ out)
{
  __shared__ float sK[81 * 64];                    // 20736 B
  __shared__ __align__(16) float sF[64 * 64 + 4];  // 16400 B (last 4 = zeros)
  const int b = blockIdx.z, h = blockIdx.y, cb = blockIdx.x * 64;
  const int tid = threadIdx.x;

  // zero scratch; full zero-init only for h<4 (those blocks skip stage(0),
  // so no ds_write vs async16 race)
  if (tid == 0) *(f32x4*)&sF[4096] = (f32x4){0.f, 0.f, 0.f, 0.f};
  if (h < 4) {
    for (int e = tid; e < 1024; e += 256)
      ((f32x4*)sF)[e] = (f32x4){0.f, 0.f, 0.f, 0.f};
  }

  // stage 81x64 kernel block; zero taps whose input row is OOB
  for (int e = tid; e < 81 * 16; e += 256) {
    int tap = e >> 4, w4 = (e & 15) * 4;
    int i = tap / 9;
    f32x4 v = {0.f, 0.f, 0.f, 0.f};
    if ((unsigned)(h - 4 + i) <= 63u)
      v = *(const f32x4*)&kern[((size_t)(b * 81) + tap) * HW2 + h * 64 + w4];
    *(f32x4*)&sK[tap * 64 + w4] = v;
  }

  const int wq = tid & 15, cs = tid >> 4;
  const int w0 = wq * 4;

  // i-invariant LDS read addresses (float indices); edge lanes -> zero scratch
  int aL[4], aM[4], aR[4];
  #pragma unroll
  for (int ch = 0; ch < 4; ++ch) {
    int base = (cs * 4 + ch) * 64 + w0;
    aM[ch] = base;
    aL[ch] = wq ? (base - 4) : 4096;
    aR[ch] = (wq != 15) ? (base + 4) : 4096;
  }

  // per-thread stage source: chunk = s*256+tid; ch = chunk>>4 = s*16+(tid>>4);
  // w-quad = (chunk&15) = (tid&15).  So per-s advance = 16 channels = 65536 f.
  const float* gsrc = feats + (((size_t)(b * 1024 + cb + (tid >> 4))) << 12) +
                      (tid & 15) * 4;

  // stage row i=0 (hh = h-4) if valid
  {
    int hh = h - 4;
    if (hh >= 0) {   // h<4 handled by zero-init; hh<=63 always here
      #pragma unroll
      for (int s = 0; s < 4; ++s)
        async16((char*)sF + (size_t)(s * 256 + tid) * 16,
                gsrc + (size_t)s * 65536 + hh * 64);
    }
  }

  f32x4 acc[4];
  #pragma unroll
  for (int ch = 0; ch < 4; ++ch) acc[ch] = (f32x4){0.f, 0.f, 0.f, 0.f};

  #pragma unroll 1
  for (int i = 0; i < 9; ++i) {
    __syncthreads();   // stage(i) + sK (first iter) visible
    float f[4][12];
    #pragma unroll
    for (int ch = 0; ch < 4; ++ch) {
      f32x4 L = *(const f32x4*)&sF[aL[ch]];
      f32x4 M = *(const f32x4*)&sF[aM[ch]];
      f32x4 R = *(const f32x4*)&sF[aR[ch]];
      f[ch][0] = L[0]; f[ch][1] = L[1]; f[ch][2]  = L[2]; f[ch][3]  = L[3];
      f[ch][4] = M[0]; f[ch][5] = M[1]; f[ch][6]  = M[2]; f[ch][7]  = M[3];
      f[ch][8] = R[0]; f[ch][9] = R[1]; f[ch][10] = R[2]; f[ch][11] = R[3];
    }
    __syncthreads();   // reads done; safe to overwrite sF
    if (i < 8) {
      int hh = h - 4 + i + 1;
      if ((unsigned)hh <= 63u) {
        #pragma unroll
        for (int s = 0; s < 4; ++s)
          async16((char*)sF + (size_t)(s * 256 + tid) * 16,
                  gsrc + (size_t)s * 65536 + hh * 64);
      }
    }
    const float* krow = &sK[i * 9 * 64 + w0];
    #pragma unroll
    for (int j = 0; j < 9; ++j) {
      const f32x4 kv = *(const f32x4*)&krow[j * 64];
      #pragma unroll
      for (int ch = 0; ch < 4; ++ch) {
        acc[ch][0] += f[ch][j]     * kv[0];
        acc[ch][1] += f[ch][j + 1] * kv[1];
        acc[ch][2] += f[ch][j + 2] * kv[2];
        acc[ch][3] += f[ch][j + 3] * kv[3];
      }
    }
  }

  #pragma unroll
  for (int ch = 0; ch < 4; ++ch)
    *(f32x4*)&out[((size_t)(b * 1024 + cb + cs * 4 + ch)) * HW2 + h * 64 + w0] =
        acc[ch];
}

// ---------------------------------------------------------------------------
extern "C" void kernel_launch(void* const* d_in, const int* in_sizes, int n_in,
                              void* d_out, int out_size, void* d_ws, size_t ws_size,
                              hipStream_t stream) {
  const float* cur  = (const float*)d_in[0];
  const float* keyl = (const float*)d_in[1];
  const float* keyh = (const float*)d_in[2];
  const float* w_r  = (const float*)d_in[3];
  const float* b_r  = (const float*)d_in[4];
  const float* w2   = (const float*)d_in[5];
  const float* b2   = (const float*)d_in[6];
  const float* w3   = (const float*)d_in[7];
  const float* b3   = (const float*)d_in[8];
  float* out = (float*)d_out;
  char* ws = (char*)d_ws;

  const size_t NEED_FAST = 57409536;
  if (ws_size >= NEED_FAST) {
    // fast path layout:
    //   cat 16.78MB | Wb1 4.72MB | Wb2 2.36MB | bufA 33.55MB [23855104,57409536)
    //   After the conv1 pair, bufA is dead; x2b [23855104,32243712),
    //   kern [40632320,45940736) and w3b [45940736,45989888) overlay it.
    //   wprep3_k MUST launch after the last bufA consumer (round-2 bug).
    unsigned short* cat  = (unsigned short*)ws;
    unsigned short* Wb1  = (unsigned short*)(ws + 16777216);
    unsigned short* Wb2  = (unsigned short*)(ws + 21495808);
    unsigned short* bufA = (unsigned short*)(ws + 23855104);
    unsigned short* x2b  = (unsigned short*)(ws + 23855104);
    float*          kern = (float*)(ws + 40632320);
    unsigned short* w3b  = (unsigned short*)(ws + 45940736);

    wprep_k<<<256, 256, 0, stream>>>(w_r, Wb1, 1024);
    wprep_k<<<128, 256, 0, stream>>>(w2,  Wb2, 512);

    tpose_k<<<dim3(32, 8, 4), 256, 0, stream>>>(cur, bufA, 32);
    conv_mfma_k<1, 1><<<dim3(64, 8), 256, 0, stream>>>(bufA, Wb1, b_r, cat, 32, 0, 16);
    tpose_k<<<dim3(32, 8, 4), 256, 0, stream>>>(keyl, bufA, 32);
    conv_mfma_k<1, 1><<<dim3(64, 8), 256, 0, stream>>>(bufA, Wb1, b_r, cat, 32, 8, 16);

    wprep3_k<<<12, 256, 0, stream>>>(w3, w3b);   // bufA dead from here on

    conv_mfma_k<1, 1><<<dim3(64, 8), 256, 0, stream>>>(cat, Wb2, b2, x2b, 16, 0, 8);

    head_mfma_k<<<256, 256, 0, stream>>>(x2b, w3b, b3, kern);
    svc_k8<<<dim3(16, 64, 4), 256, 0, stream>>>(keyh, kern, out);
  } else {
    // fallback (37.6MB): fp32-NCHW staged convs, same MFMA head (no overlap)
    unsigned short* cat  = (unsigned short*)ws;
    unsigned short* x2b  = (unsigned short*)(ws + 16777216);
    float*          kern = (float*)(ws + 25165824);
    unsigned short* Wb1  = (unsigned short*)(ws + 30474240);
    unsigned short* Wb2  = (unsigned short*)(ws + 35192832);
    unsigned short* w3b  = (unsigned short*)(ws + 37552128);

    wprep_k<<<256, 256, 0, stream>>>(w_r, Wb1, 1024);
    wprep_k<<<128, 256, 0, stream>>>(w2,  Wb2, 512);
    wprep3_k<<<12, 256, 0, stream>>>(w3, w3b);

    conv_mfma_k<0, 1><<<dim3(64, 8), 256, 0, stream>>>(cur,  Wb1, b_r, cat, 32, 0, 16);
    conv_mfma_k<0, 1><<<dim3(64, 8), 256, 0, stream>>>(keyl, Wb1, b_r, cat, 32, 8, 16);
    conv_mfma_k<1, 1><<<dim3(64, 8), 256, 0, stream>>>(cat,  Wb2, b2, x2b, 16, 0, 8);

    head_mfma_k<<<256, 256, 0, stream>>>(x2b, w3b, b3, kern);
    svc_k8<<<dim3(16, 64, 4), 256, 0, stream>>>(keyh, kern, out);
  }
}